// Round 23
// baseline (44.400 us; speedup 1.0000x reference)
//
#include <hip/hip_runtime.h>

#define C_DIM 19
#define G_DIM 8
#define H_DIM 512
#define W_DIM 512
#define B_DIM 4
#define PLANE (H_DIM * W_DIM)
#define NT    512
#define TLX   64
#define TLY   16
#define HXX   (TLX + 2)   // 66
#define HYY   (TLY + 2)   // 18
#define NRING (2 * HXX + 2 * TLY)   // 164 halo-ring pixels

__device__ __forceinline__ unsigned bf16rne(float f) {
    unsigned x = __float_as_uint(f);
    return (x + 0x7fffu + ((x >> 16) & 1u)) >> 16;
}
__device__ __forceinline__ float up_lo(unsigned u) { return __uint_as_float(u << 16); }
__device__ __forceinline__ float up_hi(unsigned u) { return __uint_as_float(u & 0xffff0000u); }

__device__ __forceinline__ float2 ntload2(const float* p) {
    unsigned long long v = __builtin_nontemporal_load((const unsigned long long*)p);
    float2 r;
    r.x = __uint_as_float((unsigned)v);
    r.y = __uint_as_float((unsigned)(v >> 32));
    return r;
}
__device__ __forceinline__ void ntstore2(float* p, float f0, float f1) {
    unsigned long long v = (unsigned long long)__float_as_uint(f0) |
                           ((unsigned long long)__float_as_uint(f1) << 32);
    __builtin_nontemporal_store(v, (unsigned long long*)p);
}

// E = softmax(100*matrix over g): E4[c][0]=g0..3, E4[c][1]=g4..7.  NO sync inside.
__device__ __forceinline__ void build_E_nosync(const float* __restrict__ matrix,
                                               float4 (*E4)[2], int tid) {
    if (tid < C_DIM) {
        const int c = tid;
        float m[G_DIM];
        float mx = -1e30f;
        #pragma unroll
        for (int g = 0; g < G_DIM; ++g) {
            m[g] = 100.0f * matrix[g * C_DIM + c];
            mx = fmaxf(mx, m[g]);
        }
        float s = 0.0f;
        #pragma unroll
        for (int g = 0; g < G_DIM; ++g) { m[g] = __expf(m[g] - mx); s += m[g]; }
        const float inv = 1.0f / s;
        E4[c][0] = make_float4(m[0]*inv, m[1]*inv, m[2]*inv, m[3]*inv);
        E4[c][1] = make_float4(m[4]*inv, m[5]*inv, m[6]*inv, m[7]*inv);
    }
}

// ---- fully fused tile kernel: 64x16 tile, 66x18 halo, 1024 blocks x 512 thr ----
// R22 base + bigger tile: halo softmax redundancy 29% -> 16%. nt out/F kept.
// NO occupancy hint (R2/R8/R16: caps trigger catastrophic spill).
__global__ __launch_bounds__(NT)
void gacrf_tile(const float* __restrict__ F,
                const float* __restrict__ logit,
                const float* __restrict__ matrix,
                float* __restrict__ out)
{
    __shared__ float4   E4[C_DIM][2];
    __shared__ uint4    ldsQ[HYY][HXX];     // 19008 B
    __shared__ unsigned ldsL[C_DIM][NT];    // 38912 B: 2 bf16 logit / thread / c

    const int tid = threadIdx.x;

    // XCD-chunked bijective swizzle (1024 blocks, chunk 128)
    const int bid = blockIdx.x;
    const int swz = (bid & 7) * 128 + (bid >> 3);
    const int b   = swz >> 8;          // 256 tiles per batch
    const int rem = swz & 255;
    const int tby = rem >> 3;          // 0..31
    const int tbx = rem & 7;           // 0..7
    const int x0  = tbx * TLX;
    const int y0  = tby * TLY;

    const int tx = tid & 31;           // 0..31 (2 px each)
    const int ty = tid >> 5;           // 0..15
    const int gx = x0 + tx * 2;
    const int gy = y0 + ty;
    const size_t pix = (size_t)gy * W_DIM + gx;

    const float* __restrict__ logit_b = logit + (size_t)b * C_DIM * PLANE;

    build_E_nosync(matrix, E4, tid);
    __syncthreads();                   // E4 ready

    // ---- phase A: interior softmax+encode, 2 px/thread; logit -> LDS (bf16) ----
    {
        const float* __restrict__ p = logit_b + pix;
        float eg[G_DIM][2];
        #pragma unroll
        for (int g = 0; g < G_DIM; ++g) { eg[g][0] = 0.0f; eg[g][1] = 0.0f; }
        float s0 = 0.0f, s1 = 0.0f;
        #pragma unroll
        for (int c = 0; c < C_DIM; ++c) {
            const float2 lv = *(const float2*)(p + (size_t)c * PLANE);
            ldsL[c][tid] = bf16rne(lv.x) | (bf16rne(lv.y) << 16);
            const float e0 = __expf(lv.x);
            const float e1 = __expf(lv.y);
            s0 += e0; s1 += e1;
            const float4 E0 = E4[c][0];
            const float4 E1 = E4[c][1];
            eg[0][0] = fmaf(E0.x, e0, eg[0][0]);  eg[0][1] = fmaf(E0.x, e1, eg[0][1]);
            eg[1][0] = fmaf(E0.y, e0, eg[1][0]);  eg[1][1] = fmaf(E0.y, e1, eg[1][1]);
            eg[2][0] = fmaf(E0.z, e0, eg[2][0]);  eg[2][1] = fmaf(E0.z, e1, eg[2][1]);
            eg[3][0] = fmaf(E0.w, e0, eg[3][0]);  eg[3][1] = fmaf(E0.w, e1, eg[3][1]);
            eg[4][0] = fmaf(E1.x, e0, eg[4][0]);  eg[4][1] = fmaf(E1.x, e1, eg[4][1]);
            eg[5][0] = fmaf(E1.y, e0, eg[5][0]);  eg[5][1] = fmaf(E1.y, e1, eg[5][1]);
            eg[6][0] = fmaf(E1.z, e0, eg[6][0]);  eg[6][1] = fmaf(E1.z, e1, eg[6][1]);
            eg[7][0] = fmaf(E1.w, e0, eg[7][0]);  eg[7][1] = fmaf(E1.w, e1, eg[7][1]);
        }
        const float i0 = 1.0f / s0;
        const float i1 = 1.0f / s1;
        uint4 u0, u1;
        u0.x = bf16rne(eg[0][0]*i0) | (bf16rne(eg[1][0]*i0) << 16);
        u0.y = bf16rne(eg[2][0]*i0) | (bf16rne(eg[3][0]*i0) << 16);
        u0.z = bf16rne(eg[4][0]*i0) | (bf16rne(eg[5][0]*i0) << 16);
        u0.w = bf16rne(eg[6][0]*i0) | (bf16rne(eg[7][0]*i0) << 16);
        u1.x = bf16rne(eg[0][1]*i1) | (bf16rne(eg[1][1]*i1) << 16);
        u1.y = bf16rne(eg[2][1]*i1) | (bf16rne(eg[3][1]*i1) << 16);
        u1.z = bf16rne(eg[4][1]*i1) | (bf16rne(eg[5][1]*i1) << 16);
        u1.w = bf16rne(eg[6][1]*i1) | (bf16rne(eg[7][1]*i1) << 16);
        ldsQ[1 + ty][1 + tx * 2]     = u0;
        ldsQ[1 + ty][1 + tx * 2 + 1] = u1;
    }

    // ---- phase B: halo ring, threads 0..163, 1 px each ----
    if (tid < NRING) {
        int hx, hy;
        if (tid < HXX)            { hx = tid;              hy = 0; }
        else if (tid < 2 * HXX)   { hx = tid - HXX;        hy = HYY - 1; }
        else if (tid < 2 * HXX + TLY) { hx = 0;            hy = 1 + (tid - 2 * HXX); }
        else                      { hx = HXX - 1;          hy = 1 + (tid - 2 * HXX - TLY); }
        const int hgx = min(max(x0 - 1 + hx, 0), W_DIM - 1);
        const int hgy = min(max(y0 - 1 + hy, 0), H_DIM - 1);
        const float* __restrict__ p = logit_b + (size_t)hgy * W_DIM + hgx;

        float eg[G_DIM];
        #pragma unroll
        for (int g = 0; g < G_DIM; ++g) eg[g] = 0.0f;
        float s = 0.0f;
        #pragma unroll
        for (int c = 0; c < C_DIM; ++c) {
            const float e = __expf(p[(size_t)c * PLANE]);
            s += e;
            const float4 E0 = E4[c][0];
            const float4 E1 = E4[c][1];
            eg[0] = fmaf(E0.x, e, eg[0]);
            eg[1] = fmaf(E0.y, e, eg[1]);
            eg[2] = fmaf(E0.z, e, eg[2]);
            eg[3] = fmaf(E0.w, e, eg[3]);
            eg[4] = fmaf(E1.x, e, eg[4]);
            eg[5] = fmaf(E1.y, e, eg[5]);
            eg[6] = fmaf(E1.z, e, eg[6]);
            eg[7] = fmaf(E1.w, e, eg[7]);
        }
        const float inv = 1.0f / s;
        uint4 u;
        u.x = bf16rne(eg[0]*inv) | (bf16rne(eg[1]*inv) << 16);
        u.y = bf16rne(eg[2]*inv) | (bf16rne(eg[3]*inv) << 16);
        u.z = bf16rne(eg[4]*inv) | (bf16rne(eg[5]*inv) << 16);
        u.w = bf16rne(eg[6]*inv) | (bf16rne(eg[7]*inv) << 16);
        ldsQ[hy][hx] = u;
    }
    __syncthreads();

    // ---- 3x3 filter from LDS; F weights loaded per-row, nontemporal ----
    const bool vyr[3] = { gy > 0, true, gy < H_DIM - 1 };
    const bool vxc[4] = { gx > 0, true, true, gx + 2 < W_DIM };
    const int lx = tx * 2;             // LDS col of (gx-1)
    const float* __restrict__ Fp = F + (size_t)b * 9 * PLANE + pix;

    float og[G_DIM][2];
    #pragma unroll
    for (int g = 0; g < G_DIM; ++g) { og[g][0] = 0.0f; og[g][1] = 0.0f; }

    #pragma unroll
    for (int r = 0; r < 3; ++r) {
        const float2 w0 = ntload2(Fp + (size_t)(r * 3 + 0) * PLANE);
        const float2 w1 = ntload2(Fp + (size_t)(r * 3 + 1) * PLANE);
        const float2 w2 = ntload2(Fp + (size_t)(r * 3 + 2) * PLANE);
        const float2 wr[3] = { w0, w1, w2 };

        const uint4 q0 = ldsQ[ty + r][lx];
        const uint4 q1 = ldsQ[ty + r][lx + 1];
        const uint4 q2 = ldsQ[ty + r][lx + 2];
        const uint4 q3 = ldsQ[ty + r][lx + 3];
        const uint4 qv_[4] = { q0, q1, q2, q3 };

        #pragma unroll
        for (int dxi = 0; dxi < 3; ++dxi) {
            const float wkv[2] = { wr[dxi].x, wr[dxi].y };
            #pragma unroll
            for (int j = 0; j < 2; ++j) {
                const bool v = vyr[r] & vxc[j + dxi];
                const float wv = v ? wkv[j] : 0.0f;
                const uint4 qv = qv_[j + dxi];
                og[0][j] = fmaf(wv, up_lo(qv.x), og[0][j]);
                og[1][j] = fmaf(wv, up_hi(qv.x), og[1][j]);
                og[2][j] = fmaf(wv, up_lo(qv.y), og[2][j]);
                og[3][j] = fmaf(wv, up_hi(qv.y), og[3][j]);
                og[4][j] = fmaf(wv, up_lo(qv.z), og[4][j]);
                og[5][j] = fmaf(wv, up_hi(qv.z), og[5][j]);
                og[6][j] = fmaf(wv, up_lo(qv.w), og[6][j]);
                og[7][j] = fmaf(wv, up_hi(qv.w), og[7][j]);
            }
        }
    }

    // ---- decode + subtract + nt-store; logit from LDS (bf16, same-thread) ----
    float* __restrict__ op = out + (size_t)b * C_DIM * PLANE + pix;
    #pragma unroll
    for (int c = 0; c < C_DIM; ++c) {
        const unsigned lw = ldsL[c][tid];
        const float4 E0 = E4[c][0];
        const float4 E1 = E4[c][1];
        float d0 = og[0][0] * E0.x;
        float d1 = og[0][1] * E0.x;
        d0 = fmaf(og[1][0], E0.y, d0);  d1 = fmaf(og[1][1], E0.y, d1);
        d0 = fmaf(og[2][0], E0.z, d0);  d1 = fmaf(og[2][1], E0.z, d1);
        d0 = fmaf(og[3][0], E0.w, d0);  d1 = fmaf(og[3][1], E0.w, d1);
        d0 = fmaf(og[4][0], E1.x, d0);  d1 = fmaf(og[4][1], E1.x, d1);
        d0 = fmaf(og[5][0], E1.y, d0);  d1 = fmaf(og[5][1], E1.y, d1);
        d0 = fmaf(og[6][0], E1.z, d0);  d1 = fmaf(og[6][1], E1.z, d1);
        d0 = fmaf(og[7][0], E1.w, d0);  d1 = fmaf(og[7][1], E1.w, d1);
        ntstore2(op + (size_t)c * PLANE, up_lo(lw) - d0, up_hi(lw) - d1);
    }
}

extern "C" void kernel_launch(void* const* d_in, const int* in_sizes, int n_in,
                              void* d_out, int out_size, void* d_ws, size_t ws_size,
                              hipStream_t stream) {
    const float* F      = (const float*)d_in[0];   // [4, 9, 512, 512]
    const float* logit  = (const float*)d_in[1];   // [4, 19, 512, 512]
    const float* matrix = (const float*)d_in[2];   // [8, 19, 1, 1]
    float* out = (float*)d_out;                    // [4, 19, 512, 512]

    gacrf_tile<<<1024, NT, 0, stream>>>(F, logit, matrix, out);
}

// Round 24
// 42.122 us; speedup vs baseline: 1.0541x; 1.0541x over previous
//
#include <hip/hip_runtime.h>

#define C_DIM 19
#define G_DIM 8
#define H_DIM 512
#define W_DIM 512
#define B_DIM 4
#define PLANE (H_DIM * W_DIM)
#define NT    256
#define TLX   64
#define TLY   8
#define HXX   (TLX + 2)   // 66
#define HYY   (TLY + 2)   // 10

__device__ __forceinline__ unsigned bf16rne(float f) {
    unsigned x = __float_as_uint(f);
    return (x + 0x7fffu + ((x >> 16) & 1u)) >> 16;
}
__device__ __forceinline__ float up_lo(unsigned u) { return __uint_as_float(u << 16); }
__device__ __forceinline__ float up_hi(unsigned u) { return __uint_as_float(u & 0xffff0000u); }

__device__ __forceinline__ float2 ntload2(const float* p) {
    unsigned long long v = __builtin_nontemporal_load((const unsigned long long*)p);
    float2 r;
    r.x = __uint_as_float((unsigned)v);
    r.y = __uint_as_float((unsigned)(v >> 32));
    return r;
}
__device__ __forceinline__ void ntstore2(float* p, float f0, float f1) {
    unsigned long long v = (unsigned long long)__float_as_uint(f0) |
                           ((unsigned long long)__float_as_uint(f1) << 32);
    __builtin_nontemporal_store(v, (unsigned long long*)p);
}

// E = softmax(100*matrix over g): E4[c][0]=g0..3, E4[c][1]=g4..7.  NO sync inside.
__device__ __forceinline__ void build_E_nosync(const float* __restrict__ matrix,
                                               float4 (*E4)[2], int tid) {
    if (tid < C_DIM) {
        const int c = tid;
        float m[G_DIM];
        float mx = -1e30f;
        #pragma unroll
        for (int g = 0; g < G_DIM; ++g) {
            m[g] = 100.0f * matrix[g * C_DIM + c];
            mx = fmaxf(mx, m[g]);
        }
        float s = 0.0f;
        #pragma unroll
        for (int g = 0; g < G_DIM; ++g) { m[g] = __expf(m[g] - mx); s += m[g]; }
        const float inv = 1.0f / s;
        E4[c][0] = make_float4(m[0]*inv, m[1]*inv, m[2]*inv, m[3]*inv);
        E4[c][1] = make_float4(m[4]*inv, m[5]*inv, m[6]*inv, m[7]*inv);
    }
}

// ---- fully fused tile kernel: 64x8 output tile, 66x10 halo, 2048 blocks ----
// Best configuration (R22, 42.1us): fused softmax+encode+filter+decode,
// 2 px/thread, logit retained in LDS as bf16, nt out-stores / F-loads,
// XCD-chunked swizzle. NO occupancy hint (R2/R8/R16 spill trap).
__global__ __launch_bounds__(NT)
void gacrf_tile(const float* __restrict__ F,
                const float* __restrict__ logit,
                const float* __restrict__ matrix,
                float* __restrict__ out)
{
    __shared__ float4   E4[C_DIM][2];
    __shared__ uint4    ldsQ[HYY][HXX];     // 10560 B
    __shared__ unsigned ldsL[C_DIM][NT];    // 19456 B: 2 bf16 logit / thread / c

    const int tid = threadIdx.x;

    // XCD-chunked bijective swizzle (2048 blocks, chunk 256)
    const int bid = blockIdx.x;
    const int swz = (bid & 7) * 256 + (bid >> 3);
    const int b   = swz >> 9;
    const int rem = swz & 511;
    const int tby = rem >> 3;          // 0..63
    const int tbx = rem & 7;           // 0..7
    const int x0  = tbx * TLX;
    const int y0  = tby * TLY;

    const int tx = tid & 31;           // 0..31 (2 px each)
    const int ty = tid >> 5;           // 0..7
    const int gx = x0 + tx * 2;
    const int gy = y0 + ty;
    const size_t pix = (size_t)gy * W_DIM + gx;

    const float* __restrict__ logit_b = logit + (size_t)b * C_DIM * PLANE;

    build_E_nosync(matrix, E4, tid);
    __syncthreads();                   // E4 ready

    // ---- phase A: interior softmax+encode, 2 px/thread; logit -> LDS (bf16) ----
    {
        const float* __restrict__ p = logit_b + pix;
        float eg[G_DIM][2];
        #pragma unroll
        for (int g = 0; g < G_DIM; ++g) { eg[g][0] = 0.0f; eg[g][1] = 0.0f; }
        float s0 = 0.0f, s1 = 0.0f;
        #pragma unroll
        for (int c = 0; c < C_DIM; ++c) {
            const float2 lv = *(const float2*)(p + (size_t)c * PLANE);
            ldsL[c][tid] = bf16rne(lv.x) | (bf16rne(lv.y) << 16);
            const float e0 = __expf(lv.x);
            const float e1 = __expf(lv.y);
            s0 += e0; s1 += e1;
            const float4 E0 = E4[c][0];
            const float4 E1 = E4[c][1];
            eg[0][0] = fmaf(E0.x, e0, eg[0][0]);  eg[0][1] = fmaf(E0.x, e1, eg[0][1]);
            eg[1][0] = fmaf(E0.y, e0, eg[1][0]);  eg[1][1] = fmaf(E0.y, e1, eg[1][1]);
            eg[2][0] = fmaf(E0.z, e0, eg[2][0]);  eg[2][1] = fmaf(E0.z, e1, eg[2][1]);
            eg[3][0] = fmaf(E0.w, e0, eg[3][0]);  eg[3][1] = fmaf(E0.w, e1, eg[3][1]);
            eg[4][0] = fmaf(E1.x, e0, eg[4][0]);  eg[4][1] = fmaf(E1.x, e1, eg[4][1]);
            eg[5][0] = fmaf(E1.y, e0, eg[5][0]);  eg[5][1] = fmaf(E1.y, e1, eg[5][1]);
            eg[6][0] = fmaf(E1.z, e0, eg[6][0]);  eg[6][1] = fmaf(E1.z, e1, eg[6][1]);
            eg[7][0] = fmaf(E1.w, e0, eg[7][0]);  eg[7][1] = fmaf(E1.w, e1, eg[7][1]);
        }
        const float i0 = 1.0f / s0;
        const float i1 = 1.0f / s1;
        uint4 u0, u1;
        u0.x = bf16rne(eg[0][0]*i0) | (bf16rne(eg[1][0]*i0) << 16);
        u0.y = bf16rne(eg[2][0]*i0) | (bf16rne(eg[3][0]*i0) << 16);
        u0.z = bf16rne(eg[4][0]*i0) | (bf16rne(eg[5][0]*i0) << 16);
        u0.w = bf16rne(eg[6][0]*i0) | (bf16rne(eg[7][0]*i0) << 16);
        u1.x = bf16rne(eg[0][1]*i1) | (bf16rne(eg[1][1]*i1) << 16);
        u1.y = bf16rne(eg[2][1]*i1) | (bf16rne(eg[3][1]*i1) << 16);
        u1.z = bf16rne(eg[4][1]*i1) | (bf16rne(eg[5][1]*i1) << 16);
        u1.w = bf16rne(eg[6][1]*i1) | (bf16rne(eg[7][1]*i1) << 16);
        ldsQ[1 + ty][1 + tx * 2]     = u0;
        ldsQ[1 + ty][1 + tx * 2 + 1] = u1;
    }

    // ---- phase B: halo ring, threads 0..147, 1 px each ----
    if (tid < 148) {
        int hx, hy;
        if (tid < 66)       { hx = tid;        hy = 0; }
        else if (tid < 132) { hx = tid - 66;   hy = 9; }
        else if (tid < 140) { hx = 0;          hy = 1 + (tid - 132); }
        else                { hx = 65;         hy = 1 + (tid - 140); }
        const int hgx = min(max(x0 - 1 + hx, 0), W_DIM - 1);
        const int hgy = min(max(y0 - 1 + hy, 0), H_DIM - 1);
        const float* __restrict__ p = logit_b + (size_t)hgy * W_DIM + hgx;

        float eg[G_DIM];
        #pragma unroll
        for (int g = 0; g < G_DIM; ++g) eg[g] = 0.0f;
        float s = 0.0f;
        #pragma unroll
        for (int c = 0; c < C_DIM; ++c) {
            const float e = __expf(p[(size_t)c * PLANE]);
            s += e;
            const float4 E0 = E4[c][0];
            const float4 E1 = E4[c][1];
            eg[0] = fmaf(E0.x, e, eg[0]);
            eg[1] = fmaf(E0.y, e, eg[1]);
            eg[2] = fmaf(E0.z, e, eg[2]);
            eg[3] = fmaf(E0.w, e, eg[3]);
            eg[4] = fmaf(E1.x, e, eg[4]);
            eg[5] = fmaf(E1.y, e, eg[5]);
            eg[6] = fmaf(E1.z, e, eg[6]);
            eg[7] = fmaf(E1.w, e, eg[7]);
        }
        const float inv = 1.0f / s;
        uint4 u;
        u.x = bf16rne(eg[0]*inv) | (bf16rne(eg[1]*inv) << 16);
        u.y = bf16rne(eg[2]*inv) | (bf16rne(eg[3]*inv) << 16);
        u.z = bf16rne(eg[4]*inv) | (bf16rne(eg[5]*inv) << 16);
        u.w = bf16rne(eg[6]*inv) | (bf16rne(eg[7]*inv) << 16);
        ldsQ[hy][hx] = u;
    }
    __syncthreads();

    // ---- 3x3 filter from LDS; F weights loaded per-row, nontemporal ----
    const bool vyr[3] = { gy > 0, true, gy < H_DIM - 1 };
    const bool vxc[4] = { gx > 0, true, true, gx + 2 < W_DIM };
    const int lx = tx * 2;             // LDS col of (gx-1)
    const float* __restrict__ Fp = F + (size_t)b * 9 * PLANE + pix;

    float og[G_DIM][2];
    #pragma unroll
    for (int g = 0; g < G_DIM; ++g) { og[g][0] = 0.0f; og[g][1] = 0.0f; }

    #pragma unroll
    for (int r = 0; r < 3; ++r) {
        const float2 w0 = ntload2(Fp + (size_t)(r * 3 + 0) * PLANE);
        const float2 w1 = ntload2(Fp + (size_t)(r * 3 + 1) * PLANE);
        const float2 w2 = ntload2(Fp + (size_t)(r * 3 + 2) * PLANE);
        const float2 wr[3] = { w0, w1, w2 };

        const uint4 q0 = ldsQ[ty + r][lx];
        const uint4 q1 = ldsQ[ty + r][lx + 1];
        const uint4 q2 = ldsQ[ty + r][lx + 2];
        const uint4 q3 = ldsQ[ty + r][lx + 3];
        const uint4 qv_[4] = { q0, q1, q2, q3 };

        #pragma unroll
        for (int dxi = 0; dxi < 3; ++dxi) {
            const float wkv[2] = { wr[dxi].x, wr[dxi].y };
            #pragma unroll
            for (int j = 0; j < 2; ++j) {
                const bool v = vyr[r] & vxc[j + dxi];
                const float wv = v ? wkv[j] : 0.0f;
                const uint4 qv = qv_[j + dxi];
                og[0][j] = fmaf(wv, up_lo(qv.x), og[0][j]);
                og[1][j] = fmaf(wv, up_hi(qv.x), og[1][j]);
                og[2][j] = fmaf(wv, up_lo(qv.y), og[2][j]);
                og[3][j] = fmaf(wv, up_hi(qv.y), og[3][j]);
                og[4][j] = fmaf(wv, up_lo(qv.z), og[4][j]);
                og[5][j] = fmaf(wv, up_hi(qv.z), og[5][j]);
                og[6][j] = fmaf(wv, up_lo(qv.w), og[6][j]);
                og[7][j] = fmaf(wv, up_hi(qv.w), og[7][j]);
            }
        }
    }

    // ---- decode + subtract + nt-store; logit from LDS (bf16, same-thread) ----
    float* __restrict__ op = out + (size_t)b * C_DIM * PLANE + pix;
    #pragma unroll
    for (int c = 0; c < C_DIM; ++c) {
        const unsigned lw = ldsL[c][tid];
        const float4 E0 = E4[c][0];
        const float4 E1 = E4[c][1];
        float d0 = og[0][0] * E0.x;
        float d1 = og[0][1] * E0.x;
        d0 = fmaf(og[1][0], E0.y, d0);  d1 = fmaf(og[1][1], E0.y, d1);
        d0 = fmaf(og[2][0], E0.z, d0);  d1 = fmaf(og[2][1], E0.z, d1);
        d0 = fmaf(og[3][0], E0.w, d0);  d1 = fmaf(og[3][1], E0.w, d1);
        d0 = fmaf(og[4][0], E1.x, d0);  d1 = fmaf(og[4][1], E1.x, d1);
        d0 = fmaf(og[5][0], E1.y, d0);  d1 = fmaf(og[5][1], E1.y, d1);
        d0 = fmaf(og[6][0], E1.z, d0);  d1 = fmaf(og[6][1], E1.z, d1);
        d0 = fmaf(og[7][0], E1.w, d0);  d1 = fmaf(og[7][1], E1.w, d1);
        ntstore2(op + (size_t)c * PLANE, up_lo(lw) - d0, up_hi(lw) - d1);
    }
}

extern "C" void kernel_launch(void* const* d_in, const int* in_sizes, int n_in,
                              void* d_out, int out_size, void* d_ws, size_t ws_size,
                              hipStream_t stream) {
    const float* F      = (const float*)d_in[0];   // [4, 9, 512, 512]
    const float* logit  = (const float*)d_in[1];   // [4, 19, 512, 512]
    const float* matrix = (const float*)d_in[2];   // [8, 19, 1, 1]
    float* out = (float*)d_out;                    // [4, 19, 512, 512]

    gacrf_tile<<<2048, NT, 0, stream>>>(F, logit, matrix, out);
}